// Round 6
// baseline (3292.681 us; speedup 1.0000x reference)
//
#include <hip/hip_runtime.h>
#include <hip/hip_bf16.h>

typedef unsigned short u16;
typedef unsigned int u32;
typedef __attribute__((ext_vector_type(8))) short bf16x8;
typedef __attribute__((ext_vector_type(4))) float f32x4;
typedef __attribute__((ext_vector_type(4))) u32 u32x4;

#define BATCH 16384
#define NLEVS 60

#define SFC_OFF ((size_t)BATCH * NLEVS * 4)
#define MEM_OFF (SFC_OFF + (size_t)BATCH * 3)

// packed u16 plane offsets (in u16 units, from wpk)
#define W1IH_HI 0
#define W1IH_LO 8192
#define W1HH_HI 16384
#define W1HH_LO 32768
#define W2IH_HI 49152
#define W2IH_LO 65536
#define W2HH_HI 81920
#define W2HH_LO 98304
#define WHD_HI  114688
#define WHD_LO  116736

#define WPK_BYTE_OFF 4096
#define WS_R1_BYTE_OFF 262144

#define MFMA(a, b, c) __builtin_amdgcn_mfma_f32_16x16x32_bf16((a), (b), (c), 0, 0, 0)

__device__ __forceinline__ float bf2f(u16 u) {
    union { u32 i; float f; } v; v.i = (u32)u << 16; return v.f;
}
__device__ __forceinline__ u16 f2bf(float f) {
    __hip_bfloat16 b = __float2bfloat16(f);
    u16 u; __builtin_memcpy(&u, &b, 2); return u;
}
__device__ __forceinline__ void split2(float w, u16& hi, u16& lo) {
    u16 h = f2bf(w);
    hi = h;
    lo = f2bf(w - bf2f(h));
}
__device__ __forceinline__ float sigm(float x) {
    float e = __builtin_amdgcn_exp2f(-1.44269504f * x);
    return __builtin_amdgcn_rcpf(1.0f + e);
}
__device__ __forceinline__ float tanh_(float x) {
    float ax = fabsf(x);
    float e  = __builtin_amdgcn_exp2f(-2.88539008f * ax);
    float t  = (1.0f - e) * __builtin_amdgcn_rcpf(1.0f + e);
    return copysignf(t, x);
}

// Pack all weights to bf16 hi/lo planes; fuse biases and Wout@Wlat head. f32 exact.
// (unchanged from round 5 — validated)
__global__ void setup_pack(const float* __restrict__ W1ih, const float* __restrict__ W1hh,
                           const float* __restrict__ W2ih, const float* __restrict__ W2hh,
                           const float* __restrict__ Wlat, const float* __restrict__ Wout,
                           const float* __restrict__ Wsfco,
                           const float* __restrict__ b1ih, const float* __restrict__ b1hh,
                           const float* __restrict__ b2ih, const float* __restrict__ b2hh,
                           const float* __restrict__ blat, const float* __restrict__ bout,
                           const float* __restrict__ bsfco,
                           float* __restrict__ wsf, u16* __restrict__ wpk)
{
    int t = blockIdx.x * 256 + threadIdx.x;
    if (t < 256) { wsf[t] = b1ih[t] + b1hh[t]; return; }
    if (t < 512) { int j = t - 256; wsf[256 + j] = b2ih[j] + b2hh[j]; return; }
    if (t < 544) {
        int j = t - 512; float v;
        if (j < 16) v = blat[j];
        else if (j < 20) { v = bout[j - 16]; for (int m = 0; m < 16; ++m) v += Wout[(j - 16) * 16 + m] * blat[m]; }
        else if (j < 23) v = bsfco[j - 20];
        else v = 0.f;
        wsf[512 + j] = v; return;
    }
    int u = t - 544;
    float w; int hi_off, lo_off, idx;
    if (u < 8192) {
        int col = u >> 5, k = u & 31;
        w = (k < 20) ? W1ih[col * 20 + k] : 0.f;
        hi_off = W1IH_HI; lo_off = W1IH_LO; idx = u;
    } else if (u < 24576) {
        idx = u - 8192; w = W1hh[idx]; hi_off = W1HH_HI; lo_off = W1HH_LO;
    } else if (u < 40960) {
        idx = u - 24576; w = W2ih[idx]; hi_off = W2IH_HI; lo_off = W2IH_LO;
    } else if (u < 57344) {
        idx = u - 40960; w = W2hh[idx]; hi_off = W2HH_HI; lo_off = W2HH_LO;
    } else if (u < 59392) {
        idx = u - 57344; int hc = idx >> 6, k = idx & 63;
        if (hc < 16) w = Wlat[hc * 64 + k];
        else if (hc < 20) { w = 0.f; for (int m = 0; m < 16; ++m) w += Wout[(hc - 16) * 16 + m] * Wlat[m * 64 + k]; }
        else if (hc < 23) w = Wsfco[(hc - 20) * 64 + k];
        else w = 0.f;
        hi_off = WHD_HI; lo_off = WHD_LO;
    } else return;
    u16 h_, l_; split2(w, h_, l_);
    wpk[hi_off + idx] = h_;
    wpk[lo_off + idx] = l_;
}

// One wave (64 threads) per block; wave owns 16 batch rows end-to-end.
// No __syncthreads anywhere; all exchange is intra-wave via private LDS.
__global__ __launch_bounds__(64, 2)
void lstm_wave(const float* __restrict__ in_main, const float* __restrict__ in_aux,
               const float* __restrict__ in_mem,
               const float* __restrict__ Wsfc1, const float* __restrict__ bsfc1,
               const float* __restrict__ Wsfc2, const float* __restrict__ bsfc2,
               const float* __restrict__ Wtoa1, const float* __restrict__ btoa1,
               const float* __restrict__ Wtoa2, const float* __restrict__ btoa2,
               const float* __restrict__ wsf, const u16* __restrict__ wpk,
               u16* __restrict__ r1h, u16* __restrict__ r1l,
               int b_off, int ch_rows, float* __restrict__ out)
{
    __shared__ __align__(16) u32 hbuf[16 * 72];   // packed (hi<<16|lo), XOR-swizzled cols

    const int lane = threadIdx.x;
    const int q   = lane >> 4;
    const int l15 = lane & 15;
    const int lloc = blockIdx.x * 16 + l15;        // chunk-local A-row (for r1ws)
    const int aRow = b_off + lloc;                 // global A-row
    const int crow = b_off + blockIdx.x * 16 + q * 4;  // global C-row base (+r)

    bf16x8 hfh[2], hfl[2];                         // h A-fragments hi/lo per k-half
    float cst[4][4];                               // c state [ntile][r]

    // ---- bias preload (phase 1)
    float b1r[4][4];
#pragma unroll
    for (int g = 0; g < 4; ++g)
#pragma unroll
        for (int nt = 0; nt < 4; ++nt)
            b1r[g][nt] = wsf[g * 64 + nt * 16 + l15];

    // ---- LSTM1 init
    {
        const float a0 = in_aux[(size_t)aRow * 3];
        const float a1 = in_aux[(size_t)aRow * 3 + 1];
        const float a2 = in_aux[(size_t)aRow * 3 + 2];
#pragma unroll
        for (int kt = 0; kt < 2; ++kt) {
            u32 dh[4], dl[4];
#pragma unroll
            for (int p = 0; p < 4; ++p) {
                int k0 = kt * 32 + q * 8 + p * 2;
                float ha = tanh_(fmaf(a0, Wsfc1[k0*3], fmaf(a1, Wsfc1[k0*3+1], fmaf(a2, Wsfc1[k0*3+2], bsfc1[k0]))));
                float hb = tanh_(fmaf(a0, Wsfc1[k0*3+3], fmaf(a1, Wsfc1[k0*3+4], fmaf(a2, Wsfc1[k0*3+5], bsfc1[k0+1]))));
                u16 hah, hal, hbh, hbl; split2(ha, hah, hal); split2(hb, hbh, hbl);
                dh[p] = ((u32)hbh << 16) | hah;
                dl[p] = ((u32)hbl << 16) | hal;
            }
            __builtin_memcpy(&hfh[kt], dh, 16);
            __builtin_memcpy(&hfl[kt], dl, 16);
        }
#pragma unroll
        for (int r = 0; r < 4; ++r) {
            const size_t gr = (size_t)(crow + r) * 3;
            float c0 = in_aux[gr], c1 = in_aux[gr + 1], c2 = in_aux[gr + 2];
#pragma unroll
            for (int nt = 0; nt < 4; ++nt) {
                int u = nt * 16 + l15;
                cst[nt][r] = tanh_(fmaf(c0, Wsfc2[u*3], fmaf(c1, Wsfc2[u*3+1], fmaf(c2, Wsfc2[u*3+2], bsfc2[u]))));
            }
        }
    }

    // ---- PHASE 1: LSTM1 over reversed levels
#pragma unroll 1
    for (int t = 0; t < NLEVS; ++t) {
        const int lev = 59 - t;
        // x1 A-fragment (K=32, k>=20 zero-padded; matches wpk W1IH padding)
        bf16x8 axh, axl;
        {
            float xv[8] = {0, 0, 0, 0, 0, 0, 0, 0};
            const size_t mi = (size_t)aRow * NLEVS + lev;
            if (q == 0) {
                float4 m = *(const float4*)(in_main + mi * 4);
                float4 e = *(const float4*)(in_mem + mi * 16);
                xv[0]=m.x; xv[1]=m.y; xv[2]=m.z; xv[3]=m.w;
                xv[4]=e.x; xv[5]=e.y; xv[6]=e.z; xv[7]=e.w;
            } else if (q == 1) {
                float4 e0 = *(const float4*)(in_mem + mi * 16 + 4);
                float4 e1 = *(const float4*)(in_mem + mi * 16 + 8);
                xv[0]=e0.x; xv[1]=e0.y; xv[2]=e0.z; xv[3]=e0.w;
                xv[4]=e1.x; xv[5]=e1.y; xv[6]=e1.z; xv[7]=e1.w;
            } else if (q == 2) {
                float4 e2 = *(const float4*)(in_mem + mi * 16 + 12);
                xv[0]=e2.x; xv[1]=e2.y; xv[2]=e2.z; xv[3]=e2.w;
            }
            u32 dh[4], dl[4];
#pragma unroll
            for (int p = 0; p < 4; ++p) {
                u16 h0, l0, h1, l1; split2(xv[p*2], h0, l0); split2(xv[p*2+1], h1, l1);
                dh[p] = ((u32)h1 << 16) | h0;
                dl[p] = ((u32)l1 << 16) | l0;
            }
            __builtin_memcpy(&axh, dh, 16);
            __builtin_memcpy(&axl, dl, 16);
        }
        // gates
#pragma unroll
        for (int nt = 0; nt < 4; ++nt) {
            f32x4 C[4];
#pragma unroll
            for (int g = 0; g < 4; ++g) {
                const int col = g * 64 + nt * 16 + l15;
                const bf16x8 Bih = *(const bf16x8*)(wpk + W1IH_HI + col * 32 + q * 8);
                const bf16x8 Bil = *(const bf16x8*)(wpk + W1IH_LO + col * 32 + q * 8);
                f32x4 a = {b1r[g][nt], b1r[g][nt], b1r[g][nt], b1r[g][nt]};
                a = MFMA(axh, Bih, a);
                a = MFMA(axl, Bih, a);
                a = MFMA(axh, Bil, a);
#pragma unroll
                for (int kt = 0; kt < 2; ++kt) {
                    const bf16x8 Bhh = *(const bf16x8*)(wpk + W1HH_HI + col * 64 + kt * 32 + q * 8);
                    const bf16x8 Bhl = *(const bf16x8*)(wpk + W1HH_LO + col * 64 + kt * 32 + q * 8);
                    a = MFMA(hfh[kt], Bhh, a);
                    a = MFMA(hfl[kt], Bhh, a);
                    a = MFMA(hfh[kt], Bhl, a);
                }
                C[g] = a;
            }
#pragma unroll
            for (int r = 0; r < 4; ++r) {
                float c = sigm(C[1][r]) * cst[nt][r] + sigm(C[0][r]) * tanh_(C[2][r]);
                cst[nt][r] = c;
                float h = sigm(C[3][r]) * tanh_(c);
                u16 hh_, hl_; split2(h, hh_, hl_);
                hbuf[(q * 4 + r) * 72 + ((nt * 16 + l15) ^ (r << 3))] = ((u32)hh_ << 16) | hl_;
            }
        }
        // read back new h A-frags (intra-wave transpose) + store rnn1out planes
#pragma unroll
        for (int kt = 0; kt < 2; ++kt) {
            u32 w[8];
            const int cb = (kt * 32 + q * 8) ^ ((l15 & 3) << 3);
            *(u32x4*)&w[0] = *(const u32x4*)&hbuf[l15 * 72 + cb];
            *(u32x4*)&w[4] = *(const u32x4*)&hbuf[l15 * 72 + cb + 4];
            u32 dh[4], dl[4];
#pragma unroll
            for (int p = 0; p < 4; ++p) {
                dh[p] = (w[p*2] >> 16) | (w[p*2+1] & 0xffff0000u);
                dl[p] = (w[p*2] & 0xffffu) | (w[p*2+1] << 16);
            }
            __builtin_memcpy(&hfh[kt], dh, 16);
            __builtin_memcpy(&hfl[kt], dl, 16);
            const size_t ro = ((size_t)lev * ch_rows + lloc) * 64 + kt * 32 + q * 8;
            *(u32x4*)(r1h + ro) = *(const u32x4*)dh;
            *(u32x4*)(r1l + ro) = *(const u32x4*)dl;
        }
    }

    // ---- LSTM2 init
    {
        const float toa = in_aux[(size_t)aRow * 3 + 1];
#pragma unroll
        for (int kt = 0; kt < 2; ++kt) {
            u32 dh[4], dl[4];
#pragma unroll
            for (int p = 0; p < 4; ++p) {
                int k0 = kt * 32 + q * 8 + p * 2;
                float ha = fmaf(toa, Wtoa2[k0],     btoa2[k0]);
                float hb = fmaf(toa, Wtoa2[k0 + 1], btoa2[k0 + 1]);
                u16 hah, hal, hbh, hbl; split2(ha, hah, hal); split2(hb, hbh, hbl);
                dh[p] = ((u32)hbh << 16) | hah;
                dl[p] = ((u32)hbl << 16) | hal;
            }
            __builtin_memcpy(&hfh[kt], dh, 16);
            __builtin_memcpy(&hfl[kt], dl, 16);
        }
#pragma unroll
        for (int r = 0; r < 4; ++r) {
            const float toc = in_aux[(size_t)(crow + r) * 3 + 1];
#pragma unroll
            for (int nt = 0; nt < 4; ++nt) {
                int u = nt * 16 + l15;
                cst[nt][r] = fmaf(toc, Wtoa1[u], btoa1[u]);
            }
        }
    }

    float b2r[4][4], bhd[2];
#pragma unroll
    for (int g = 0; g < 4; ++g)
#pragma unroll
        for (int nt = 0; nt < 4; ++nt)
            b2r[g][nt] = wsf[256 + g * 64 + nt * 16 + l15];
    bhd[0] = wsf[512 + l15];
    bhd[1] = wsf[528 + l15];

    // ---- PHASE 2: LSTM2 forward + fused heads
#pragma unroll 1
    for (int lev = 0; lev < NLEVS; ++lev) {
        bf16x8 axh[2], axl[2];
#pragma unroll
        for (int kt = 0; kt < 2; ++kt) {
            const size_t ro = ((size_t)lev * ch_rows + lloc) * 64 + kt * 32 + q * 8;
            axh[kt] = *(const bf16x8*)(r1h + ro);
            axl[kt] = *(const bf16x8*)(r1l + ro);
        }
#pragma unroll
        for (int nt = 0; nt < 4; ++nt) {
            f32x4 C[4];
#pragma unroll
            for (int g = 0; g < 4; ++g) {
                const int col = g * 64 + nt * 16 + l15;
                f32x4 a = {b2r[g][nt], b2r[g][nt], b2r[g][nt], b2r[g][nt]};
#pragma unroll
                for (int kt = 0; kt < 2; ++kt) {
                    const bf16x8 Bih = *(const bf16x8*)(wpk + W2IH_HI + col * 64 + kt * 32 + q * 8);
                    const bf16x8 Bil = *(const bf16x8*)(wpk + W2IH_LO + col * 64 + kt * 32 + q * 8);
                    const bf16x8 Bhh = *(const bf16x8*)(wpk + W2HH_HI + col * 64 + kt * 32 + q * 8);
                    const bf16x8 Bhl = *(const bf16x8*)(wpk + W2HH_LO + col * 64 + kt * 32 + q * 8);
                    a = MFMA(axh[kt], Bih, a);
                    a = MFMA(axl[kt], Bih, a);
                    a = MFMA(axh[kt], Bil, a);
                    a = MFMA(hfh[kt], Bhh, a);
                    a = MFMA(hfl[kt], Bhh, a);
                    a = MFMA(hfh[kt], Bhl, a);
                }
                C[g] = a;
            }
#pragma unroll
            for (int r = 0; r < 4; ++r) {
                float c = sigm(C[1][r]) * cst[nt][r] + sigm(C[0][r]) * tanh_(C[2][r]);
                cst[nt][r] = c;
                float h = sigm(C[3][r]) * tanh_(c);
                u16 hh_, hl_; split2(h, hh_, hl_);
                hbuf[(q * 4 + r) * 72 + ((nt * 16 + l15) ^ (r << 3))] = ((u32)hh_ << 16) | hl_;
            }
        }
        // read back h2 A-frags
#pragma unroll
        for (int kt = 0; kt < 2; ++kt) {
            u32 w[8];
            const int cb = (kt * 32 + q * 8) ^ ((l15 & 3) << 3);
            *(u32x4*)&w[0] = *(const u32x4*)&hbuf[l15 * 72 + cb];
            *(u32x4*)&w[4] = *(const u32x4*)&hbuf[l15 * 72 + cb + 4];
            u32 dh[4], dl[4];
#pragma unroll
            for (int p = 0; p < 4; ++p) {
                dh[p] = (w[p*2] >> 16) | (w[p*2+1] & 0xffff0000u);
                dl[p] = (w[p*2] & 0xffffu) | (w[p*2+1] << 16);
            }
            __builtin_memcpy(&hfh[kt], dh, 16);
            __builtin_memcpy(&hfl[kt], dl, 16);
        }
        // heads on current h2: cols 0..15 = Wlat (mem_new), 16..19 = Wout@Wlat (out),
        // 20..22 = Wsfco (out_sfc, lev 59 only)
#pragma unroll
        for (int hnt = 0; hnt < 2; ++hnt) {
            const int col = hnt * 16 + l15;
            f32x4 a = {bhd[hnt], bhd[hnt], bhd[hnt], bhd[hnt]};
#pragma unroll
            for (int kt = 0; kt < 2; ++kt) {
                const bf16x8 Bh = *(const bf16x8*)(wpk + WHD_HI + col * 64 + kt * 32 + q * 8);
                const bf16x8 Bl = *(const bf16x8*)(wpk + WHD_LO + col * 64 + kt * 32 + q * 8);
                a = MFMA(hfh[kt], Bh, a);
                a = MFMA(hfl[kt], Bh, a);
                a = MFMA(hfh[kt], Bl, a);
            }
#pragma unroll
            for (int r = 0; r < 4; ++r) {
                const size_t gb = (size_t)(crow + r);
                if (hnt == 0) {
                    out[MEM_OFF + (gb * NLEVS + lev) * 16 + l15] = tanh_(a[r]);
                } else {
                    if (l15 < 4) out[(gb * NLEVS + lev) * 4 + l15] = a[r];
                    else if (l15 < 7 && lev == 59) out[SFC_OFF + gb * 3 + (l15 - 4)] = a[r];
                }
            }
        }
    }
}

extern "C" void kernel_launch(void* const* d_in, const int* in_sizes, int n_in,
                              void* d_out, int out_size, void* d_ws, size_t ws_size,
                              hipStream_t stream) {
    const float* in_main = (const float*)d_in[0];
    const float* in_aux  = (const float*)d_in[1];
    const float* in_mem  = (const float*)d_in[2];
    const float* Wsfc1   = (const float*)d_in[3];
    const float* bsfc1   = (const float*)d_in[4];
    const float* Wsfc2   = (const float*)d_in[5];
    const float* bsfc2   = (const float*)d_in[6];
    const float* Wtoa1   = (const float*)d_in[7];
    const float* btoa1   = (const float*)d_in[8];
    const float* Wtoa2   = (const float*)d_in[9];
    const float* btoa2   = (const float*)d_in[10];
    const float* W1ih    = (const float*)d_in[11];
    const float* W1hh    = (const float*)d_in[12];
    const float* b1ih    = (const float*)d_in[13];
    const float* b1hh    = (const float*)d_in[14];
    const float* W2ih    = (const float*)d_in[15];
    const float* W2hh    = (const float*)d_in[16];
    const float* b2ih    = (const float*)d_in[17];
    const float* b2hh    = (const float*)d_in[18];
    const float* Wlat    = (const float*)d_in[19];
    const float* blat    = (const float*)d_in[20];
    const float* Wout    = (const float*)d_in[21];
    const float* bout    = (const float*)d_in[22];
    const float* Wsfco   = (const float*)d_in[23];
    const float* bsfco   = (const float*)d_in[24];
    float* out           = (float*)d_out;

    float* wsf    = (float*)d_ws;
    u16*   wpk    = (u16*)((char*)d_ws + WPK_BYTE_OFF);
    u16*   r1base = (u16*)((char*)d_ws + WS_R1_BYTE_OFF);

    setup_pack<<<235, 256, 0, stream>>>(W1ih, W1hh, W2ih, W2hh, Wlat, Wout, Wsfco,
                                        b1ih, b1hh, b2ih, b2hh, blat, bout, bsfco,
                                        wsf, wpk);

    const size_t avail = (ws_size > WS_R1_BYTE_OFF) ? ws_size - WS_R1_BYTE_OFF : 0;
    const size_t per_row = (size_t)NLEVS * 64 * 2 * 2;   // 30720 B (hi+lo planes)
    size_t rows = avail / per_row;
    rows &= ~(size_t)15;
    if (rows > BATCH) rows = BATCH;
    if (rows < 16) rows = 16;

    for (int off = 0; off < BATCH; off += (int)rows) {
        int nr = (BATCH - off < (int)rows) ? (BATCH - off) : (int)rows;
        u16* r1h = r1base;
        u16* r1l = r1base + (size_t)NLEVS * nr * 64;
        lstm_wave<<<nr / 16, 64, 0, stream>>>(
            in_main, in_aux, in_mem, Wsfc1, bsfc1, Wsfc2, bsfc2,
            Wtoa1, btoa1, Wtoa2, btoa2, wsf, wpk, r1h, r1l, off, nr, out);
    }
}

// Round 7
// 544.923 us; speedup vs baseline: 6.0425x; 6.0425x over previous
//
#include <hip/hip_runtime.h>
#include <hip/hip_bf16.h>

typedef unsigned short u16;
typedef unsigned int u32;
typedef __attribute__((ext_vector_type(8))) short bf16x8;
typedef __attribute__((ext_vector_type(4))) float f32x4;
typedef __attribute__((ext_vector_type(4))) u32 u32x4;

#define BATCH 16384
#define NLEVS 60

#define SFC_OFF ((size_t)BATCH * NLEVS * 4)
#define MEM_OFF (SFC_OFF + (size_t)BATCH * 3)

// packed u16 plane offsets (in u16 units, from wpk) — layout validated r5/r6
#define W1IH_HI 0
#define W1IH_LO 8192
#define W1HH_HI 16384
#define W1HH_LO 32768
#define W2IH_HI 49152
#define W2IH_LO 65536
#define W2HH_HI 81920
#define W2HH_LO 98304
#define WHD_HI  114688
#define WHD_LO  116736

#define WPK_BYTE_OFF 4096
#define WS_R1_BYTE_OFF 262144

#define MFMA(a, b, c) __builtin_amdgcn_mfma_f32_16x16x32_bf16((a), (b), (c), 0, 0, 0)

__device__ __forceinline__ float bf2f(u16 u) {
    union { u32 i; float f; } v; v.i = (u32)u << 16; return v.f;
}
__device__ __forceinline__ u16 f2bf(float f) {
    __hip_bfloat16 b = __float2bfloat16(f);
    u16 u; __builtin_memcpy(&u, &b, 2); return u;
}
__device__ __forceinline__ void split2(float w, u16& hi, u16& lo) {
    u16 h = f2bf(w);
    hi = h;
    lo = f2bf(w - bf2f(h));
}
__device__ __forceinline__ float sigm(float x) {
    float e = __builtin_amdgcn_exp2f(-1.44269504f * x);
    return __builtin_amdgcn_rcpf(1.0f + e);
}
__device__ __forceinline__ float tanh_(float x) {
    float ax = fabsf(x);
    float e  = __builtin_amdgcn_exp2f(-2.88539008f * ax);
    float t  = (1.0f - e) * __builtin_amdgcn_rcpf(1.0f + e);
    return copysignf(t, x);
}

// LDS swizzles — single definition used by BOTH stager and reader.
// K=32 matrices (64B/col), chunk q4 in [0,4):
__device__ __forceinline__ int swz32(int c, int q4) { return c * 64 + ((q4 * 16) ^ ((c & 3) << 4)); }
// K=64 matrices (128B/col), chunk qk = kt*4+q in [0,8):
__device__ __forceinline__ int swz64(int c, int qk) { return c * 128 + ((qk * 16) ^ ((c & 7) << 4)); }

// Pack all weights to bf16 hi/lo planes; fuse biases and Wout@Wlat head. (validated r5/r6)
__global__ void setup_pack(const float* __restrict__ W1ih, const float* __restrict__ W1hh,
                           const float* __restrict__ W2ih, const float* __restrict__ W2hh,
                           const float* __restrict__ Wlat, const float* __restrict__ Wout,
                           const float* __restrict__ Wsfco,
                           const float* __restrict__ b1ih, const float* __restrict__ b1hh,
                           const float* __restrict__ b2ih, const float* __restrict__ b2hh,
                           const float* __restrict__ blat, const float* __restrict__ bout,
                           const float* __restrict__ bsfco,
                           float* __restrict__ wsf, u16* __restrict__ wpk)
{
    int t = blockIdx.x * 256 + threadIdx.x;
    if (t < 256) { wsf[t] = b1ih[t] + b1hh[t]; return; }
    if (t < 512) { int j = t - 256; wsf[256 + j] = b2ih[j] + b2hh[j]; return; }
    if (t < 544) {
        int j = t - 512; float v;
        if (j < 16) v = blat[j];
        else if (j < 20) { v = bout[j - 16]; for (int m = 0; m < 16; ++m) v += Wout[(j - 16) * 16 + m] * blat[m]; }
        else if (j < 23) v = bsfco[j - 20];
        else v = 0.f;
        wsf[512 + j] = v; return;
    }
    int u = t - 544;
    float w; int hi_off, lo_off, idx;
    if (u < 8192) {
        int col = u >> 5, k = u & 31;
        w = (k < 20) ? W1ih[col * 20 + k] : 0.f;
        hi_off = W1IH_HI; lo_off = W1IH_LO; idx = u;
    } else if (u < 24576) {
        idx = u - 8192; w = W1hh[idx]; hi_off = W1HH_HI; lo_off = W1HH_LO;
    } else if (u < 40960) {
        idx = u - 24576; w = W2ih[idx]; hi_off = W2IH_HI; lo_off = W2IH_LO;
    } else if (u < 57344) {
        idx = u - 40960; w = W2hh[idx]; hi_off = W2HH_HI; lo_off = W2HH_LO;
    } else if (u < 59392) {
        idx = u - 57344; int hc = idx >> 6, k = idx & 63;
        if (hc < 16) w = Wlat[hc * 64 + k];
        else if (hc < 20) { w = 0.f; for (int m = 0; m < 16; ++m) w += Wout[(hc - 16) * 16 + m] * Wlat[m * 64 + k]; }
        else if (hc < 23) w = Wsfco[(hc - 20) * 64 + k];
        else w = 0.f;
        hi_off = WHD_HI; lo_off = WHD_LO;
    } else return;
    u16 h_, l_; split2(w, h_, l_);
    wpk[hi_off + idx] = h_;
    wpk[lo_off + idx] = l_;
}

// ============ Kernel 1: LSTM1 over reversed levels ============
// 256 thr = 4 waves x 16 rows. Weights in LDS (one barrier); waves autonomous after.
#define K1_IH_H 0
#define K1_IH_L 16384
#define K1_HH_H 32768
#define K1_HH_L 65536
#define K1_HB   98304
__global__ __launch_bounds__(256, 1)
void lstm1_kern(const float* __restrict__ in_main, const float* __restrict__ in_aux,
                const float* __restrict__ in_mem,
                const float* __restrict__ Wsfc1, const float* __restrict__ bsfc1,
                const float* __restrict__ Wsfc2, const float* __restrict__ bsfc2,
                const float* __restrict__ wsf, const u16* __restrict__ wpk,
                u16* __restrict__ r1h, u16* __restrict__ r1l,
                int b_off, int ch_rows)
{
    __shared__ __align__(16) char s[116736];
    const int tid = threadIdx.x;
    for (int i = tid; i < 1024; i += 256) {
        int c = i >> 2, q4 = i & 3;
        *(u32x4*)(s + K1_IH_H + swz32(c, q4)) = *(const u32x4*)(wpk + W1IH_HI + c * 32 + q4 * 8);
        *(u32x4*)(s + K1_IH_L + swz32(c, q4)) = *(const u32x4*)(wpk + W1IH_LO + c * 32 + q4 * 8);
    }
    for (int i = tid; i < 2048; i += 256) {
        int c = i >> 3, qk = i & 7;
        *(u32x4*)(s + K1_HH_H + swz64(c, qk)) = *(const u32x4*)(wpk + W1HH_HI + c * 64 + qk * 8);
        *(u32x4*)(s + K1_HH_L + swz64(c, qk)) = *(const u32x4*)(wpk + W1HH_LO + c * 64 + qk * 8);
    }
    __syncthreads();   // the ONLY barrier; LDS weights read-only below

    const int lane = tid & 63, wv = tid >> 6;
    const int q = lane >> 4, l15 = lane & 15;
    const int lloc = blockIdx.x * 64 + wv * 16 + l15;
    const int aRow = b_off + lloc;
    const int crow = b_off + blockIdx.x * 64 + wv * 16 + q * 4;
    u32* hb = (u32*)(s + K1_HB) + wv * 1152;   // wave-private 16x72 u32

    bf16x8 hfh[2], hfl[2];
    float cst[4][4];
    float b1r[4][4];
#pragma unroll
    for (int g = 0; g < 4; ++g)
#pragma unroll
        for (int nt = 0; nt < 4; ++nt)
            b1r[g][nt] = wsf[g * 64 + nt * 16 + l15];

    // init h0 (A-frag layout) and c0 (C-layout)
    {
        const float a0 = in_aux[(size_t)aRow * 3];
        const float a1 = in_aux[(size_t)aRow * 3 + 1];
        const float a2 = in_aux[(size_t)aRow * 3 + 2];
#pragma unroll
        for (int kt = 0; kt < 2; ++kt) {
            u32 dh[4], dl[4];
#pragma unroll
            for (int p = 0; p < 4; ++p) {
                int k0 = kt * 32 + q * 8 + p * 2;
                float ha = tanh_(fmaf(a0, Wsfc1[k0*3], fmaf(a1, Wsfc1[k0*3+1], fmaf(a2, Wsfc1[k0*3+2], bsfc1[k0]))));
                float hbv = tanh_(fmaf(a0, Wsfc1[k0*3+3], fmaf(a1, Wsfc1[k0*3+4], fmaf(a2, Wsfc1[k0*3+5], bsfc1[k0+1]))));
                u16 hah, hal, hbh, hbl; split2(ha, hah, hal); split2(hbv, hbh, hbl);
                dh[p] = ((u32)hbh << 16) | hah;
                dl[p] = ((u32)hbl << 16) | hal;
            }
            __builtin_memcpy(&hfh[kt], dh, 16);
            __builtin_memcpy(&hfl[kt], dl, 16);
        }
#pragma unroll
        for (int r = 0; r < 4; ++r) {
            const size_t gr = (size_t)(crow + r) * 3;
            float c0 = in_aux[gr], c1 = in_aux[gr + 1], c2 = in_aux[gr + 2];
#pragma unroll
            for (int nt = 0; nt < 4; ++nt) {
                int u = nt * 16 + l15;
                cst[nt][r] = tanh_(fmaf(c0, Wsfc2[u*3], fmaf(c1, Wsfc2[u*3+1], fmaf(c2, Wsfc2[u*3+2], bsfc2[u]))));
            }
        }
    }

    // x prefetch (lev 59)
    float4 XA = {0,0,0,0}, XB = {0,0,0,0};
    {
        const size_t mi = (size_t)aRow * NLEVS + 59;
        if (q == 0)      { XA = *(const float4*)(in_main + mi * 4);      XB = *(const float4*)(in_mem + mi * 16); }
        else if (q == 1) { XA = *(const float4*)(in_mem + mi * 16 + 4);  XB = *(const float4*)(in_mem + mi * 16 + 8); }
        else if (q == 2) { XA = *(const float4*)(in_mem + mi * 16 + 12); }
    }

#pragma unroll 1
    for (int t = 0; t < NLEVS; ++t) {
        const int lev = 59 - t;
        // consume prefetched x into A-frag (K=32, k>=20 zero-padded)
        bf16x8 axh, axl;
        {
            float xv[8] = {0, 0, 0, 0, 0, 0, 0, 0};
            if (q == 0)      { xv[0]=XA.x; xv[1]=XA.y; xv[2]=XA.z; xv[3]=XA.w; xv[4]=XB.x; xv[5]=XB.y; xv[6]=XB.z; xv[7]=XB.w; }
            else if (q == 1) { xv[0]=XA.x; xv[1]=XA.y; xv[2]=XA.z; xv[3]=XA.w; xv[4]=XB.x; xv[5]=XB.y; xv[6]=XB.z; xv[7]=XB.w; }
            else if (q == 2) { xv[0]=XA.x; xv[1]=XA.y; xv[2]=XA.z; xv[3]=XA.w; }
            u32 dh[4], dl[4];
#pragma unroll
            for (int p = 0; p < 4; ++p) {
                u16 h0, l0, h1, l1; split2(xv[p*2], h0, l0); split2(xv[p*2+1], h1, l1);
                dh[p] = ((u32)h1 << 16) | h0;
                dl[p] = ((u32)l1 << 16) | l0;
            }
            __builtin_memcpy(&axh, dh, 16);
            __builtin_memcpy(&axl, dl, 16);
        }
        // issue next-lev loads; latency hides under compute below
        if (t < 59) {
            const size_t mi = (size_t)aRow * NLEVS + (lev - 1);
            if (q == 0)      { XA = *(const float4*)(in_main + mi * 4);      XB = *(const float4*)(in_mem + mi * 16); }
            else if (q == 1) { XA = *(const float4*)(in_mem + mi * 16 + 4);  XB = *(const float4*)(in_mem + mi * 16 + 8); }
            else if (q == 2) { XA = *(const float4*)(in_mem + mi * 16 + 12); }
        }
        // gates
#pragma unroll
        for (int nt = 0; nt < 4; ++nt) {
            f32x4 C[4];
#pragma unroll
            for (int g = 0; g < 4; ++g) {
                const int col = g * 64 + nt * 16 + l15;
                const bf16x8 Bih = *(const bf16x8*)(s + K1_IH_H + swz32(col, q));
                const bf16x8 Bil = *(const bf16x8*)(s + K1_IH_L + swz32(col, q));
                f32x4 a = {b1r[g][nt], b1r[g][nt], b1r[g][nt], b1r[g][nt]};
                a = MFMA(axh, Bih, a);
                a = MFMA(axl, Bih, a);
                a = MFMA(axh, Bil, a);
#pragma unroll
                for (int kt = 0; kt < 2; ++kt) {
                    const bf16x8 Bhh = *(const bf16x8*)(s + K1_HH_H + swz64(col, kt * 4 + q));
                    const bf16x8 Bhl = *(const bf16x8*)(s + K1_HH_L + swz64(col, kt * 4 + q));
                    a = MFMA(hfh[kt], Bhh, a);
                    a = MFMA(hfl[kt], Bhh, a);
                    a = MFMA(hfh[kt], Bhl, a);
                }
                C[g] = a;
            }
#pragma unroll
            for (int r = 0; r < 4; ++r) {
                float c = sigm(C[1][r]) * cst[nt][r] + sigm(C[0][r]) * tanh_(C[2][r]);
                cst[nt][r] = c;
                float h = sigm(C[3][r]) * tanh_(c);
                u16 hh_, hl_; split2(h, hh_, hl_);
                hb[(q * 4 + r) * 72 + ((nt * 16 + l15) ^ (r << 3))] = ((u32)hh_ << 16) | hl_;
            }
        }
        // transpose-readback (wave-private LDS) + r1 store
#pragma unroll
        for (int kt = 0; kt < 2; ++kt) {
            u32 w[8];
            const int cb = (kt * 32 + q * 8) ^ ((l15 & 3) << 3);
            *(u32x4*)&w[0] = *(const u32x4*)&hb[l15 * 72 + cb];
            *(u32x4*)&w[4] = *(const u32x4*)&hb[l15 * 72 + cb + 4];
            u32 dh[4], dl[4];
#pragma unroll
            for (int p = 0; p < 4; ++p) {
                dh[p] = (w[p*2] >> 16) | (w[p*2+1] & 0xffff0000u);
                dl[p] = (w[p*2] & 0xffffu) | (w[p*2+1] << 16);
            }
            __builtin_memcpy(&hfh[kt], dh, 16);
            __builtin_memcpy(&hfl[kt], dl, 16);
            const size_t ro = ((size_t)lev * ch_rows + lloc) * 64 + kt * 32 + q * 8;
            *(u32x4*)(r1h + ro) = *(const u32x4*)dh;
            *(u32x4*)(r1l + ro) = *(const u32x4*)dl;
        }
    }
}

// ============ Kernel 2: LSTM2 forward + fused heads ============
#define K2_IH_H 0
#define K2_IH_L 32768
#define K2_HH_H 65536
#define K2_HH_L 98304
#define K2_HD_H 131072
#define K2_HD_L 135168
#define K2_HB   139264
__global__ __launch_bounds__(256, 1)
void lstm2_kern(const float* __restrict__ in_aux,
                const float* __restrict__ Wtoa1, const float* __restrict__ btoa1,
                const float* __restrict__ Wtoa2, const float* __restrict__ btoa2,
                const float* __restrict__ wsf, const u16* __restrict__ wpk,
                const u16* __restrict__ r1h, const u16* __restrict__ r1l,
                int b_off, int ch_rows, float* __restrict__ out)
{
    __shared__ __align__(16) char s[157696];
    const int tid = threadIdx.x;
    for (int i = tid; i < 2048; i += 256) {
        int c = i >> 3, qk = i & 7;
        *(u32x4*)(s + K2_IH_H + swz64(c, qk)) = *(const u32x4*)(wpk + W2IH_HI + c * 64 + qk * 8);
        *(u32x4*)(s + K2_IH_L + swz64(c, qk)) = *(const u32x4*)(wpk + W2IH_LO + c * 64 + qk * 8);
        *(u32x4*)(s + K2_HH_H + swz64(c, qk)) = *(const u32x4*)(wpk + W2HH_HI + c * 64 + qk * 8);
        *(u32x4*)(s + K2_HH_L + swz64(c, qk)) = *(const u32x4*)(wpk + W2HH_LO + c * 64 + qk * 8);
    }
    for (int i = tid; i < 256; i += 256) {
        int c = i >> 3, qk = i & 7;
        *(u32x4*)(s + K2_HD_H + swz64(c, qk)) = *(const u32x4*)(wpk + WHD_HI + c * 64 + qk * 8);
        *(u32x4*)(s + K2_HD_L + swz64(c, qk)) = *(const u32x4*)(wpk + WHD_LO + c * 64 + qk * 8);
    }
    __syncthreads();   // the ONLY barrier

    const int lane = tid & 63, wv = tid >> 6;
    const int q = lane >> 4, l15 = lane & 15;
    const int lloc = blockIdx.x * 64 + wv * 16 + l15;
    const int aRow = b_off + lloc;
    const int crow = b_off + blockIdx.x * 64 + wv * 16 + q * 4;
    u32* hb = (u32*)(s + K2_HB) + wv * 1152;

    bf16x8 hfh[2], hfl[2];
    float cst[4][4];
    float b2r[4][4], bhd[2];
#pragma unroll
    for (int g = 0; g < 4; ++g)
#pragma unroll
        for (int nt = 0; nt < 4; ++nt)
            b2r[g][nt] = wsf[256 + g * 64 + nt * 16 + l15];
    bhd[0] = wsf[512 + l15];
    bhd[1] = wsf[528 + l15];

    // init h2_0 / c2_0
    {
        const float toa = in_aux[(size_t)aRow * 3 + 1];
#pragma unroll
        for (int kt = 0; kt < 2; ++kt) {
            u32 dh[4], dl[4];
#pragma unroll
            for (int p = 0; p < 4; ++p) {
                int k0 = kt * 32 + q * 8 + p * 2;
                float ha = fmaf(toa, Wtoa2[k0],     btoa2[k0]);
                float hbv = fmaf(toa, Wtoa2[k0 + 1], btoa2[k0 + 1]);
                u16 hah, hal, hbh, hbl; split2(ha, hah, hal); split2(hbv, hbh, hbl);
                dh[p] = ((u32)hbh << 16) | hah;
                dl[p] = ((u32)hbl << 16) | hal;
            }
            __builtin_memcpy(&hfh[kt], dh, 16);
            __builtin_memcpy(&hfl[kt], dl, 16);
        }
#pragma unroll
        for (int r = 0; r < 4; ++r) {
            const float toc = in_aux[(size_t)(crow + r) * 3 + 1];
#pragma unroll
            for (int nt = 0; nt < 4; ++nt) {
                int u = nt * 16 + l15;
                cst[nt][r] = fmaf(toc, Wtoa1[u], btoa1[u]);
            }
        }
    }

    // prefetch r1 frags for lev 0
    bf16x8 pxh[2], pxl[2];
#pragma unroll
    for (int kt = 0; kt < 2; ++kt) {
        const size_t ro = ((size_t)0 * ch_rows + lloc) * 64 + kt * 32 + q * 8;
        pxh[kt] = *(const bf16x8*)(r1h + ro);
        pxl[kt] = *(const bf16x8*)(r1l + ro);
    }

#pragma unroll 1
    for (int lev = 0; lev < NLEVS; ++lev) {
        bf16x8 axh[2], axl[2];
        axh[0] = pxh[0]; axh[1] = pxh[1];
        axl[0] = pxl[0]; axl[1] = pxl[1];
        if (lev < 59) {
#pragma unroll
            for (int kt = 0; kt < 2; ++kt) {
                const size_t ro = ((size_t)(lev + 1) * ch_rows + lloc) * 64 + kt * 32 + q * 8;
                pxh[kt] = *(const bf16x8*)(r1h + ro);
                pxl[kt] = *(const bf16x8*)(r1l + ro);
            }
        }
#pragma unroll
        for (int nt = 0; nt < 4; ++nt) {
            f32x4 C[4];
#pragma unroll
            for (int g = 0; g < 4; ++g) {
                const int col = g * 64 + nt * 16 + l15;
                f32x4 a = {b2r[g][nt], b2r[g][nt], b2r[g][nt], b2r[g][nt]};
#pragma unroll
                for (int kt = 0; kt < 2; ++kt) {
                    const bf16x8 Bih = *(const bf16x8*)(s + K2_IH_H + swz64(col, kt * 4 + q));
                    const bf16x8 Bil = *(const bf16x8*)(s + K2_IH_L + swz64(col, kt * 4 + q));
                    const bf16x8 Bhh = *(const bf16x8*)(s + K2_HH_H + swz64(col, kt * 4 + q));
                    const bf16x8 Bhl = *(const bf16x8*)(s + K2_HH_L + swz64(col, kt * 4 + q));
                    a = MFMA(axh[kt], Bih, a);
                    a = MFMA(axl[kt], Bih, a);
                    a = MFMA(axh[kt], Bil, a);
                    a = MFMA(hfh[kt], Bhh, a);
                    a = MFMA(hfl[kt], Bhh, a);
                    a = MFMA(hfh[kt], Bhl, a);
                }
                C[g] = a;
            }
#pragma unroll
            for (int r = 0; r < 4; ++r) {
                float c = sigm(C[1][r]) * cst[nt][r] + sigm(C[0][r]) * tanh_(C[2][r]);
                cst[nt][r] = c;
                float h = sigm(C[3][r]) * tanh_(c);
                u16 hh_, hl_; split2(h, hh_, hl_);
                hb[(q * 4 + r) * 72 + ((nt * 16 + l15) ^ (r << 3))] = ((u32)hh_ << 16) | hl_;
            }
        }
        // transpose-readback
#pragma unroll
        for (int kt = 0; kt < 2; ++kt) {
            u32 w[8];
            const int cb = (kt * 32 + q * 8) ^ ((l15 & 3) << 3);
            *(u32x4*)&w[0] = *(const u32x4*)&hb[l15 * 72 + cb];
            *(u32x4*)&w[4] = *(const u32x4*)&hb[l15 * 72 + cb + 4];
            u32 dh[4], dl[4];
#pragma unroll
            for (int p = 0; p < 4; ++p) {
                dh[p] = (w[p*2] >> 16) | (w[p*2+1] & 0xffff0000u);
                dl[p] = (w[p*2] & 0xffffu) | (w[p*2+1] << 16);
            }
            __builtin_memcpy(&hfh[kt], dh, 16);
            __builtin_memcpy(&hfl[kt], dl, 16);
        }
        // heads on current h2: cols 0..15 Wlat (mem_new), 16..19 Wout@Wlat (out),
        // 20..22 Wsfco (out_sfc, lev 59 only)
#pragma unroll
        for (int hnt = 0; hnt < 2; ++hnt) {
            const int col = hnt * 16 + l15;
            f32x4 a = {bhd[hnt], bhd[hnt], bhd[hnt], bhd[hnt]};
#pragma unroll
            for (int kt = 0; kt < 2; ++kt) {
                const bf16x8 Bh = *(const bf16x8*)(s + K2_HD_H + swz64(col, kt * 4 + q));
                const bf16x8 Bl = *(const bf16x8*)(s + K2_HD_L + swz64(col, kt * 4 + q));
                a = MFMA(hfh[kt], Bh, a);
                a = MFMA(hfl[kt], Bh, a);
                a = MFMA(hfh[kt], Bl, a);
            }
#pragma unroll
            for (int r = 0; r < 4; ++r) {
                const size_t gb = (size_t)(crow + r);
                if (hnt == 0) {
                    out[MEM_OFF + (gb * NLEVS + lev) * 16 + l15] = tanh_(a[r]);
                } else {
                    if (l15 < 4) out[(gb * NLEVS + lev) * 4 + l15] = a[r];
                    else if (l15 < 7 && lev == 59) out[SFC_OFF + gb * 3 + (l15 - 4)] = a[r];
                }
            }
        }
    }
}

extern "C" void kernel_launch(void* const* d_in, const int* in_sizes, int n_in,
                              void* d_out, int out_size, void* d_ws, size_t ws_size,
                              hipStream_t stream) {
    const float* in_main = (const float*)d_in[0];
    const float* in_aux  = (const float*)d_in[1];
    const float* in_mem  = (const float*)d_in[2];
    const float* Wsfc1   = (const float*)d_in[3];
    const float* bsfc1   = (const float*)d_in[4];
    const float* Wsfc2   = (const float*)d_in[5];
    const float* bsfc2   = (const float*)d_in[6];
    const float* Wtoa1   = (const float*)d_in[7];
    const float* btoa1   = (const float*)d_in[8];
    const float* Wtoa2   = (const float*)d_in[9];
    const float* btoa2   = (const float*)d_in[10];
    const float* W1ih    = (const float*)d_in[11];
    const float* W1hh    = (const float*)d_in[12];
    const float* b1ih    = (const float*)d_in[13];
    const float* b1hh    = (const float*)d_in[14];
    const float* W2ih    = (const float*)d_in[15];
    const float* W2hh    = (const float*)d_in[16];
    const float* b2ih    = (const float*)d_in[17];
    const float* b2hh    = (const float*)d_in[18];
    const float* Wlat    = (const float*)d_in[19];
    const float* blat    = (const float*)d_in[20];
    const float* Wout    = (const float*)d_in[21];
    const float* bout    = (const float*)d_in[22];
    const float* Wsfco   = (const float*)d_in[23];
    const float* bsfco   = (const float*)d_in[24];
    float* out           = (float*)d_out;

    float* wsf    = (float*)d_ws;
    u16*   wpk    = (u16*)((char*)d_ws + WPK_BYTE_OFF);
    u16*   r1base = (u16*)((char*)d_ws + WS_R1_BYTE_OFF);

    setup_pack<<<235, 256, 0, stream>>>(W1ih, W1hh, W2ih, W2hh, Wlat, Wout, Wsfco,
                                        b1ih, b1hh, b2ih, b2hh, blat, bout, bsfco,
                                        wsf, wpk);

    const size_t avail = (ws_size > WS_R1_BYTE_OFF) ? ws_size - WS_R1_BYTE_OFF : 0;
    const size_t per_row = (size_t)NLEVS * 64 * 2 * 2;   // 30720/2 hi+lo u16 = 15360 B... (60*64*2B*2planes)
    size_t rows = avail / per_row;
    rows &= ~(size_t)63;
    if (rows > BATCH) rows = BATCH;
    if (rows < 64) rows = 64;

    for (int off = 0; off < BATCH; off += (int)rows) {
        int nr = (BATCH - off < (int)rows) ? (BATCH - off) : (int)rows;
        u16* r1h = r1base;
        u16* r1l = r1base + (size_t)NLEVS * nr * 64;
        lstm1_kern<<<nr / 64, 256, 0, stream>>>(
            in_main, in_aux, in_mem, Wsfc1, bsfc1, Wsfc2, bsfc2,
            wsf, wpk, r1h, r1l, off, nr);
        lstm2_kern<<<nr / 64, 256, 0, stream>>>(
            in_aux, Wtoa1, btoa1, Wtoa2, btoa2,
            wsf, wpk, r1h, r1l, off, nr, out);
    }
}